// Round 9
// baseline (207.319 us; speedup 1.0000x reference)
//
#include <hip/hip_runtime.h>
#include <hip/hip_bf16.h>
#include <math.h>

typedef __attribute__((ext_vector_type(8))) short short8;
typedef __attribute__((ext_vector_type(4))) float f32x4;
typedef __attribute__((ext_vector_type(4))) short short4v;
typedef __attribute__((ext_vector_type(2))) int int2v;

static __device__ __forceinline__ short f2bf(float f) {
    __hip_bfloat16 h = __float2bfloat16(f);
    return *reinterpret_cast<short*>(&h);
}
static __device__ __forceinline__ void store_out(float* p, float v) { *p = v; }
static __device__ __forceinline__ void store_out(short* p, float v) { *p = f2bf(v); }

#define GLL16(g, l) __builtin_amdgcn_global_load_lds( \
    (const __attribute__((address_space(1))) void*)(g), \
    (__attribute__((address_space(3))) void*)(l), 16, 0, 0)

#if __has_builtin(__builtin_amdgcn_exp2f)
#define EXP2(x) __builtin_amdgcn_exp2f(x)
#else
#define EXP2(x) exp2f(x)
#endif

// pack two f32 -> packed bf16 pair (low = a, high = b)
#if __has_builtin(__builtin_amdgcn_cvt_pk_bf16_f32)
typedef __attribute__((ext_vector_type(2))) __bf16 bf16x2;
static __device__ __forceinline__ int pack2bf(float a, float b) {
    bf16x2 r = __builtin_amdgcn_cvt_pk_bf16_f32(a, b);
    return __builtin_bit_cast(int, r);
}
#else
static __device__ __forceinline__ int pack2bf(float a, float b) {
    unsigned ua = __builtin_bit_cast(unsigned, a) + 0x8000u;
    unsigned ub = __builtin_bit_cast(unsigned, b) + 0x8000u;
    return (int)((ua >> 16) | (ub & 0xFFFF0000u));
}
#endif

struct BTrue  { static constexpr bool v = true;  };
struct BFalse { static constexpr bool v = false; };

// ---------------- fused prep: cast x -> bf16; transpose+cast both weights ----
static __device__ __forceinline__ void transpose_cast_tile(
    const float* __restrict__ W, short* __restrict__ Wt, int Kd, int N,
    int bx, int by)
{
    __shared__ float ts[32][33];
    const int c0 = bx * 32, r0 = by * 32;
    const int tx = threadIdx.x & 31, ty = threadIdx.x >> 5;   // ty 0..7
    #pragma unroll
    for (int e = 0; e < 4; ++e)
        ts[ty + e * 8][tx] = W[(size_t)(r0 + ty + e * 8) * N + c0 + tx];
    __syncthreads();
    #pragma unroll
    for (int e = 0; e < 4; ++e)
        Wt[(size_t)(c0 + ty + e * 8) * Kd + r0 + tx] = f2bf(ts[tx][ty + e * 8]);
}

__global__ __launch_bounds__(256) void prep_kernel(
    const float* __restrict__ x,      short* __restrict__ xb,    int nx,       // nx/1024 blocks
    const float* __restrict__ W_qkv,  short* __restrict__ Wt1,                 // C x 3C
    const float* __restrict__ W_proj, short* __restrict__ Wt2,                 // C x C
    int C)
{
    const int nbx = nx / 1024;                 // cast blocks
    const int nb1 = (3 * C / 32) * (C / 32);   // W_qkv tiles
    int bid = blockIdx.x;
    if (bid < nbx) {
        int i = (bid * 256 + threadIdx.x) * 4;
        float4 v = *(const float4*)(x + i);
        short4v o = { f2bf(v.x), f2bf(v.y), f2bf(v.z), f2bf(v.w) };
        *(short4v*)(xb + i) = o;
        return;
    }
    bid -= nbx;
    if (bid < nb1) {
        const int nc = 3 * C / 32;
        transpose_cast_tile(W_qkv, Wt1, C, 3 * C, bid % nc, bid / nc);
        return;
    }
    bid -= nb1;
    {
        const int nc = C / 32;
        transpose_cast_tile(W_proj, Wt2, C, C, bid % nc, bid / nc);
    }
}

// ---------------- V transpose: qkv [B,K,3C] -> Vt [B,H,DH,K] (bf16) ----------------
__global__ __launch_bounds__(256) void vtrans_kernel(
    const short* __restrict__ qkvb, short* __restrict__ vt, int K, int C)
{
    __shared__ short Vs[64][72];
    const int k0 = blockIdx.x * 64, h = blockIdx.y, b = blockIdx.z;
    const size_t rs = (size_t)3 * C;
    const short* src = qkvb + (size_t)b * K * rs + 2 * C + h * 64;
    const int key = threadIdx.x >> 3, d0 = (threadIdx.x & 7) * 8;
    *(short8*)&Vs[key][d0]      = *(const short8*)(src + (size_t)(k0 + key) * rs + d0);
    *(short8*)&Vs[key + 32][d0] = *(const short8*)(src + (size_t)(k0 + key + 32) * rs + d0);
    __syncthreads();
    const int d = threadIdx.x >> 2, kc = threadIdx.x & 3;
    short* dst = vt + ((size_t)(b * 16 + h) * 64 + d) * K + k0 + kc * 16;
    short8 o0, o1;
    #pragma unroll
    for (int j = 0; j < 8; ++j) { o0[j] = Vs[kc * 16 + j][d]; o1[j] = Vs[kc * 16 + 8 + j][d]; }
    *(short8*)dst = o0;
    *(short8*)(dst + 8) = o1;
}

// ---------------- MFMA bf16 GEMM (m97 structure): C = A @ Bt^T + bias --------
// Columns c < qcols get an extra *qscale (folds softmax scale into Q).
#define GM 128
#define GN 128
#define GK 32

template <typename OutT>
__global__ __launch_bounds__(256) void gemm_mfma_kernel(
    const short* __restrict__ A, const short* __restrict__ Bt,
    const float* __restrict__ bias, OutT* __restrict__ C,
    int M, int N, int Kd, int qcols, float qscale)
{
    __shared__ __attribute__((aligned(16))) short As[GM * GK];
    __shared__ __attribute__((aligned(16))) short Bs[GN * GK];
    const int tid  = threadIdx.x;
    const int lane = tid & 63, w = tid >> 6;
    const int col  = lane & 15, quad = lane >> 4;
    const int wm = (w & 1) * 64, wn = (w >> 1) * 64;
    const int row0 = blockIdx.y * GM, col0 = blockIdx.x * GN;
    const float sc = (col0 < qcols) ? qscale : 1.f;   // block-uniform (GN | qcols)

    const int sr = tid >> 2, scg = (tid & 3) * 8;
    const short* gA = A  + (size_t)(row0 + sr) * Kd + scg;
    const short* gB = Bt + (size_t)(col0 + sr) * Kd + scg;
    short* lA = As + sr * GK + scg;
    short* lB = Bs + sr * GK + scg;
    const size_t skip = (size_t)64 * Kd;

    f32x4 acc[4][4] = {};
    for (int k0 = 0; k0 < Kd; k0 += GK) {
        __syncthreads();
        GLL16(gA,        lA);
        GLL16(gA + skip, lA + 64 * GK);
        GLL16(gB,        lB);
        GLL16(gB + skip, lB + 64 * GK);
        gA += GK; gB += GK;
        __syncthreads();

        short8 aF[4], bF[4];
        #pragma unroll
        for (int mt = 0; mt < 4; ++mt)
            aF[mt] = *(const short8*)&As[(wm + mt * 16 + col) * GK + quad * 8];
        #pragma unroll
        for (int nt = 0; nt < 4; ++nt)
            bF[nt] = *(const short8*)&Bs[(wn + nt * 16 + col) * GK + quad * 8];
        #pragma unroll
        for (int mt = 0; mt < 4; ++mt)
            #pragma unroll
            for (int nt = 0; nt < 4; ++nt)
                acc[mt][nt] = __builtin_amdgcn_mfma_f32_16x16x32_bf16(aF[mt], bF[nt], acc[mt][nt], 0, 0, 0);
    }

    #pragma unroll
    for (int mt = 0; mt < 4; ++mt)
        #pragma unroll
        for (int i = 0; i < 4; ++i) {
            const size_t r = row0 + wm + mt * 16 + quad * 4 + i;
            #pragma unroll
            for (int nt = 0; nt < 4; ++nt) {
                const int c = col0 + wn + nt * 16 + col;
                store_out(&C[r * N + c], (acc[mt][nt][i] + bias[c]) * sc);
            }
        }
}

// ---------------- MFMA flash attention (causal) — 32 q/wave, reg-resident K/V
// 2 waves/block, each wave owns 32 queries of a 64-q tile (two 16-q MFMA
// groups sharing one set of K/V fragments -> LDS reads amortized 2x).
// Fixed-shift softmax: Q pre-scaled by scale*log2e in GEMM1, p = exp2(s).
// Row-sums on MFMA pipe via ones-column fragment. Pair-balanced tiles,
// XCD-local 1-D grid (idx%8 == h%8). K rows pi-swizzled at staging.
#define DH 64
#define FKT 64

__global__ __launch_bounds__(128) void flash_mfma_kernel(
    const short* __restrict__ qkvb,   // bf16 [B,K,3C] (Q pre-scaled)
    const short* __restrict__ vt,     // bf16 [B,H,DH,K]
    short* __restrict__ y,            // bf16 [B,K,C]
    int K, int C)
{
    __shared__ __attribute__((aligned(16))) short Ks2[2 * 64 * 32];   // [half][pi(key)][dhoff]
    __shared__ __attribute__((aligned(16))) short Vs2[2 * 64 * 32];   // [half][dh][koff]
    __shared__ __attribute__((aligned(16))) short Pt[2][32][72];      // [wave][q-row][key k]

    const int tid  = threadIdx.x;
    const int lane = tid & 63, w = tid >> 6;      // w in {0,1}
    const int col  = lane & 15, quad = lane >> 4;

    const int cmb  = blockIdx.x & 31;       // b*16+h
    const int g    = blockIdx.x >> 5;       // pair index 0..15
    const int b    = cmb >> 4, h = cmb & 15;
    const int NT   = K / 64;                // 32 query tiles

    // ones-column B fragment: L = P @ ones = rowsum
    short8 bOnes;
    #pragma unroll
    for (int j = 0; j < 8; ++j) bOnes[j] = (col == 0) ? (short)0x3F80 : (short)0;

    const size_t rs = (size_t)3 * C;
    const short* qbase = qkvb + (size_t)b * K * rs + h * DH;
    const short* kbase = qbase + C;
    const short* vbase = vt + (size_t)(b * 16 + h) * DH * K;

    auto run = [&](int t0) {
        const int q0 = t0 + w * 32;

        short8 aQ[2][2];
        #pragma unroll
        for (int qg = 0; qg < 2; ++qg) {
            const short* qp = qbase + (size_t)(q0 + qg * 16 + col) * rs;
            aQ[qg][0] = *(const short8*)(qp + quad * 8);
            aQ[qg][1] = *(const short8*)(qp + 32 + quad * 8);
        }
        f32x4 O[2][4] = {};
        f32x4 L4[2] = {};

        const int nkt = t0 / FKT + 1;
        for (int it = 0; it < nkt; ++it) {
            const int kt = it * FKT;
            __syncthreads();                 // prior iter's LDS reads done
            // ---- stage K (pi-swizzled rows) and V^T : 16 segs x 1KB, 8/wave ----
            #pragma unroll
            for (int cc = 0; cc < 4; ++cc) {
                const int seg  = w * 4 + cc;                 // 0..7
                const int half = seg >> 2, kseg = seg & 3;
                const int rowl = kseg * 16 + (lane >> 2);
                const int grow = rowl ^ ((rowl >> 2) & 3);   // pi for K rows
                const int off  = half * 32 + (lane & 3) * 8;
                GLL16(kbase + (size_t)(kt + grow) * rs + off, &Ks2[seg * 512 + lane * 8]);
                GLL16(vbase + (size_t)rowl * K + kt + off,    &Vs2[seg * 512 + lane * 8]);
            }
            __syncthreads();                 // staging visible

            // ---- K/V fragments: read ONCE, reused by both q-groups ----
            short8 bK[4][2], bV[4][2];
            #pragma unroll
            for (int nb = 0; nb < 4; ++nb) {
                const int prow = (col * 4 + nb) ^ (col & 3);   // pi(key)
                bK[nb][0] = *(const short8*)&Ks2[prow * 32 + quad * 8];
                bK[nb][1] = *(const short8*)&Ks2[2048 + prow * 32 + quad * 8];
            }
            #pragma unroll
            for (int db = 0; db < 4; ++db) {
                bV[db][0] = *(const short8*)&Vs2[(db * 16 + col) * 32 + quad * 8];
                bV[db][1] = *(const short8*)&Vs2[2048 + (db * 16 + col) * 32 + quad * 8];
            }

            #pragma unroll
            for (int qg = 0; qg < 2; ++qg) {
                const int qb = q0 + qg * 16;

                // ---- S = Q K^T ; slot (nb,col) = key col*4+nb ----
                f32x4 S[4] = {};
                #pragma unroll
                for (int nb = 0; nb < 4; ++nb) {
                    S[nb] = __builtin_amdgcn_mfma_f32_16x16x32_bf16(aQ[qg][0], bK[nb][0], S[nb], 0, 0, 0);
                    S[nb] = __builtin_amdgcn_mfma_f32_16x16x32_bf16(aQ[qg][1], bK[nb][1], S[nb], 0, 0, 0);
                }

                // ---- p = exp2(s) (Q pre-scaled), mask on diagonal tiles ----
                auto smax = [&](auto tag) {
                    constexpr bool MASKED = decltype(tag)::v;
                    #pragma unroll
                    for (int i = 0; i < 4; ++i) {
                        const int q = qb + quad * 4 + i;
                        float sv0 = S[0][i], sv1 = S[1][i], sv2 = S[2][i], sv3 = S[3][i];
                        if constexpr (MASKED) {
                            const int kc4 = kt + col * 4;
                            sv0 = (kc4 + 0 <= q) ? sv0 : -INFINITY;
                            sv1 = (kc4 + 1 <= q) ? sv1 : -INFINITY;
                            sv2 = (kc4 + 2 <= q) ? sv2 : -INFINITY;
                            sv3 = (kc4 + 3 <= q) ? sv3 : -INFINITY;
                        }
                        const float p0 = EXP2(sv0);
                        const float p1 = EXP2(sv1);
                        const float p2 = EXP2(sv2);
                        const float p3 = EXP2(sv3);
                        int2v pw = { pack2bf(p0, p1), pack2bf(p2, p3) };
                        *(int2v*)&Pt[w][qg * 16 + quad * 4 + i][col * 4] = pw;
                    }
                };
                if (kt + 63 <= qb) smax(BFalse{}); else smax(BTrue{});

                asm volatile("s_waitcnt lgkmcnt(0)" ::: "memory");   // P visible in-wave

                // ---- O += P V ; L += P @ ones ----
                #pragma unroll
                for (int half = 0; half < 2; ++half) {
                    short8 aP = *(const short8*)&Pt[w][qg * 16 + col][half * 32 + quad * 8];
                    #pragma unroll
                    for (int db = 0; db < 4; ++db)
                        O[qg][db] = __builtin_amdgcn_mfma_f32_16x16x32_bf16(aP, bV[db][half], O[qg][db], 0, 0, 0);
                    L4[qg] = __builtin_amdgcn_mfma_f32_16x16x32_bf16(aP, bOnes, L4[qg], 0, 0, 0);
                }
            }
        }

        // ---- epilogue: broadcast row-sum from col0 lane, normalize, store ----
        #pragma unroll
        for (int qg = 0; qg < 2; ++qg)
            #pragma unroll
            for (int i = 0; i < 4; ++i) {
                const float l = __shfl(L4[qg][i], quad * 16, 64);
                const float inv = 1.f / l;
                const int q = q0 + qg * 16 + quad * 4 + i;
                short* yr = y + ((size_t)b * K + q) * C + h * DH;
                #pragma unroll
                for (int db = 0; db < 4; ++db)
                    yr[db * 16 + col] = f2bf(O[qg][db][i] * inv);
            }
    };

    run(g * 64);                 // low-work tile
    run((NT - 1 - g) * 64);      // mirror tile (balanced: 33 iters total)
}

// ------------------------------- launch -------------------------------------
extern "C" void kernel_launch(void* const* d_in, const int* in_sizes, int n_in,
                              void* d_out, int out_size, void* d_ws, size_t ws_size,
                              hipStream_t stream)
{
    const float* x      = (const float*)d_in[0];
    const float* W_qkv  = (const float*)d_in[1];
    const float* b_qkv  = (const float*)d_in[2];
    const float* W_proj = (const float*)d_in[3];
    const float* b_proj = (const float*)d_in[4];

    const int B = 2, K = 2048, C = 1024, H = 16;
    const int M = B * K;   // 4096
    const float C2 = 0.18033688f;   // (1/sqrt(64)) * log2(e)

    char* ws = (char*)d_ws;
    short* xb    = (short*)ws;  ws += (size_t)M * C * 2;          // 8.4 MB
    short* Wt1   = (short*)ws;  ws += (size_t)3 * C * C * 2;      // 6.3 MB
    short* Wt2   = (short*)ws;  ws += (size_t)C * C * 2;          // 2.1 MB
    short* qkvb  = (short*)ws;  ws += (size_t)M * 3 * C * 2;      // 25.2 MB
    short* yb    = (short*)ws;  ws += (size_t)M * C * 2;          // 8.4 MB
    short* vtb   = (short*)ws;                                    // 8.4 MB

    // prep (fused): cast x + transpose both weights
    const int nbx = (M * C) / 1024;                       // 4096
    const int nb1 = (3 * C / 32) * (C / 32);              // 3072
    const int nb2 = (C / 32) * (C / 32);                  // 1024
    prep_kernel<<<nbx + nb1 + nb2, 256, 0, stream>>>(x, xb, M * C, W_qkv, Wt1, W_proj, Wt2, C);

    // 1) qkv = x @ W_qkv + b_qkv  (bf16 out; Q columns pre-scaled by C2)
    dim3 g1((3 * C) / GN, M / GM);
    gemm_mfma_kernel<short><<<g1, 256, 0, stream>>>(xb, Wt1, b_qkv, qkvb, M, 3 * C, C, C, C2);

    // 1b) V transpose for flash B-fragments
    dim3 gv(K / 64, H, B);
    vtrans_kernel<<<gv, 256, 0, stream>>>(qkvb, vtb, K, C);

    // 2) flash attention -> yb (bf16); 1-D grid: idx = pair*32 + (b*16+h)
    const int NPAIR = (K / 64) / 2;   // 16
    flash_mfma_kernel<<<dim3(NPAIR * 32), 128, 0, stream>>>(qkvb, vtb, yb, K, C);

    // 3) out = y @ W_proj + b_proj (fp32 out)
    dim3 g3(C / GN, M / GM);
    gemm_mfma_kernel<float><<<g3, 256, 0, stream>>>(yb, Wt2, b_proj, (float*)d_out, M, C, C, 0, 1.f);
}

// Round 10
// 192.892 us; speedup vs baseline: 1.0748x; 1.0748x over previous
//
#include <hip/hip_runtime.h>
#include <hip/hip_bf16.h>
#include <math.h>

typedef __attribute__((ext_vector_type(8))) short short8;
typedef __attribute__((ext_vector_type(4))) float f32x4;
typedef __attribute__((ext_vector_type(4))) short short4v;
typedef __attribute__((ext_vector_type(2))) int int2v;

static __device__ __forceinline__ short f2bf(float f) {
    __hip_bfloat16 h = __float2bfloat16(f);
    return *reinterpret_cast<short*>(&h);
}
static __device__ __forceinline__ void store_out(float* p, float v) { *p = v; }
static __device__ __forceinline__ void store_out(short* p, float v) { *p = f2bf(v); }

#define GLL16(g, l) __builtin_amdgcn_global_load_lds( \
    (const __attribute__((address_space(1))) void*)(g), \
    (__attribute__((address_space(3))) void*)(l), 16, 0, 0)

#if __has_builtin(__builtin_amdgcn_exp2f)
#define EXP2(x) __builtin_amdgcn_exp2f(x)
#else
#define EXP2(x) exp2f(x)
#endif

// pack two f32 -> packed bf16 pair (low = a, high = b)
#if __has_builtin(__builtin_amdgcn_cvt_pk_bf16_f32)
typedef __attribute__((ext_vector_type(2))) __bf16 bf16x2;
static __device__ __forceinline__ int pack2bf(float a, float b) {
    bf16x2 r = __builtin_amdgcn_cvt_pk_bf16_f32(a, b);
    return __builtin_bit_cast(int, r);
}
#else
static __device__ __forceinline__ int pack2bf(float a, float b) {
    unsigned ua = __builtin_bit_cast(unsigned, a) + 0x8000u;
    unsigned ub = __builtin_bit_cast(unsigned, b) + 0x8000u;
    return (int)((ua >> 16) | (ub & 0xFFFF0000u));
}
#endif

// ---------------- fused prep: cast x -> bf16; transpose+cast both weights ----
static __device__ __forceinline__ void transpose_cast_tile(
    const float* __restrict__ W, short* __restrict__ Wt, int Kd, int N,
    int bx, int by)
{
    __shared__ float ts[32][33];
    const int c0 = bx * 32, r0 = by * 32;
    const int tx = threadIdx.x & 31, ty = threadIdx.x >> 5;   // ty 0..7
    #pragma unroll
    for (int e = 0; e < 4; ++e)
        ts[ty + e * 8][tx] = W[(size_t)(r0 + ty + e * 8) * N + c0 + tx];
    __syncthreads();
    #pragma unroll
    for (int e = 0; e < 4; ++e)
        Wt[(size_t)(c0 + ty + e * 8) * Kd + r0 + tx] = f2bf(ts[tx][ty + e * 8]);
}

__global__ __launch_bounds__(256) void prep_kernel(
    const float* __restrict__ x,      short* __restrict__ xb,    int nx,
    const float* __restrict__ W_qkv,  short* __restrict__ Wt1,
    const float* __restrict__ W_proj, short* __restrict__ Wt2,
    int C)
{
    const int nbx = nx / 1024;
    const int nb1 = (3 * C / 32) * (C / 32);
    int bid = blockIdx.x;
    if (bid < nbx) {
        int i = (bid * 256 + threadIdx.x) * 4;
        float4 v = *(const float4*)(x + i);
        short4v o = { f2bf(v.x), f2bf(v.y), f2bf(v.z), f2bf(v.w) };
        *(short4v*)(xb + i) = o;
        return;
    }
    bid -= nbx;
    if (bid < nb1) {
        const int nc = 3 * C / 32;
        transpose_cast_tile(W_qkv, Wt1, C, 3 * C, bid % nc, bid / nc);
        return;
    }
    bid -= nb1;
    {
        const int nc = C / 32;
        transpose_cast_tile(W_proj, Wt2, C, C, bid % nc, bid / nc);
    }
}

// ---------------- V transpose: qkv [B,K,3C] -> Vt [B,H,DH,K] (bf16) ----------------
__global__ __launch_bounds__(256) void vtrans_kernel(
    const short* __restrict__ qkvb, short* __restrict__ vt, int K, int C)
{
    __shared__ short Vs[64][72];
    const int k0 = blockIdx.x * 64, h = blockIdx.y, b = blockIdx.z;
    const size_t rs = (size_t)3 * C;
    const short* src = qkvb + (size_t)b * K * rs + 2 * C + h * 64;
    const int key = threadIdx.x >> 3, d0 = (threadIdx.x & 7) * 8;
    *(short8*)&Vs[key][d0]      = *(const short8*)(src + (size_t)(k0 + key) * rs + d0);
    *(short8*)&Vs[key + 32][d0] = *(const short8*)(src + (size_t)(k0 + key + 32) * rs + d0);
    __syncthreads();
    const int d = threadIdx.x >> 2, kc = threadIdx.x & 3;
    short* dst = vt + ((size_t)(b * 16 + h) * 64 + d) * K + k0 + kc * 16;
    short8 o0, o1;
    #pragma unroll
    for (int j = 0; j < 8; ++j) { o0[j] = Vs[kc * 16 + j][d]; o1[j] = Vs[kc * 16 + 8 + j][d]; }
    *(short8*)dst = o0;
    *(short8*)(dst + 8) = o1;
}

// ---------------- MFMA bf16 GEMM (m97 structure): C = A @ Bt^T + bias --------
// Columns c < qcols get an extra *qscale (folds softmax scale into Q).
#define GM 128
#define GN 128
#define GK 32

template <typename OutT>
__global__ __launch_bounds__(256) void gemm_mfma_kernel(
    const short* __restrict__ A, const short* __restrict__ Bt,
    const float* __restrict__ bias, OutT* __restrict__ C,
    int M, int N, int Kd, int qcols, float qscale)
{
    __shared__ __attribute__((aligned(16))) short As[GM * GK];
    __shared__ __attribute__((aligned(16))) short Bs[GN * GK];
    const int tid  = threadIdx.x;
    const int lane = tid & 63, w = tid >> 6;
    const int col  = lane & 15, quad = lane >> 4;
    const int wm = (w & 1) * 64, wn = (w >> 1) * 64;
    const int row0 = blockIdx.y * GM, col0 = blockIdx.x * GN;
    const float sc = (col0 < qcols) ? qscale : 1.f;

    const int sr = tid >> 2, scg = (tid & 3) * 8;
    const short* gA = A  + (size_t)(row0 + sr) * Kd + scg;
    const short* gB = Bt + (size_t)(col0 + sr) * Kd + scg;
    short* lA = As + sr * GK + scg;
    short* lB = Bs + sr * GK + scg;
    const size_t skip = (size_t)64 * Kd;

    f32x4 acc[4][4] = {};
    for (int k0 = 0; k0 < Kd; k0 += GK) {
        __syncthreads();
        GLL16(gA,        lA);
        GLL16(gA + skip, lA + 64 * GK);
        GLL16(gB,        lB);
        GLL16(gB + skip, lB + 64 * GK);
        gA += GK; gB += GK;
        __syncthreads();

        short8 aF[4], bF[4];
        #pragma unroll
        for (int mt = 0; mt < 4; ++mt)
            aF[mt] = *(const short8*)&As[(wm + mt * 16 + col) * GK + quad * 8];
        #pragma unroll
        for (int nt = 0; nt < 4; ++nt)
            bF[nt] = *(const short8*)&Bs[(wn + nt * 16 + col) * GK + quad * 8];
        #pragma unroll
        for (int mt = 0; mt < 4; ++mt)
            #pragma unroll
            for (int nt = 0; nt < 4; ++nt)
                acc[mt][nt] = __builtin_amdgcn_mfma_f32_16x16x32_bf16(aF[mt], bF[nt], acc[mt][nt], 0, 0, 0);
    }

    #pragma unroll
    for (int mt = 0; mt < 4; ++mt)
        #pragma unroll
        for (int i = 0; i < 4; ++i) {
            const size_t r = row0 + wm + mt * 16 + quad * 4 + i;
            #pragma unroll
            for (int nt = 0; nt < 4; ++nt) {
                const int c = col0 + wn + nt * 16 + col;
                store_out(&C[r * N + c], (acc[mt][nt][i] + bias[c]) * sc);
            }
        }
}

// ---------------- MFMA flash attention (causal) — split-K, barrier-free -----
// Block = 4 waves, one 64-q tile at a time (pair-balanced: tile g then 31-g).
// Each wave owns every 4th 64-key chunk, staged into its PRIVATE 16.6 KB LDS
// region (K: 8 blocks x 1040 B with bit-swap row perm; V^T likewise). No
// __syncthreads in the K loop — waves self-pace on vmcnt(0); fixed-shift
// softmax (p = exp2(s), Q pre-scaled in GEMM1) makes O/l sums associative so
// per-wave partials reduce once per tile via LDS (overlaid on staging space).
// Row-sums ride the MFMA pipe via a ones-column fragment. 2048 waves = 8/CU.
#define DH 64

__global__ __launch_bounds__(256, 2) void flash_mfma_kernel(
    const short* __restrict__ qkvb,   // bf16 [B,K,3C] (Q pre-scaled)
    const short* __restrict__ vt,     // bf16 [B,H,DH,K]
    short* __restrict__ y,            // bf16 [B,K,C]
    int K, int C)
{
    // per-wave: K 8*520=4160 sh, V 4160 sh; Pt 16*72=1152 sh. total 37888 sh = 75.8 KB
    __shared__ __attribute__((aligned(16))) short smem[37888];

    const int tid  = threadIdx.x;
    const int lane = tid & 63, w = tid >> 6;
    const int col  = lane & 15, quad = lane >> 4;

    short* Ksw = smem + w * 4160;
    short* Vsw = smem + 16640 + w * 4160;
    short* Ptw = smem + 33280 + w * 1152;
    float* Or  = (float*)smem;            // 64 x 68 f32 (17.4 KB), overlays K/V

    const int cmb = blockIdx.x & 31;      // b*16+h  (XCD-local: idx%8 tracks h)
    const int g   = blockIdx.x >> 5;      // pair index 0..15
    const int b   = cmb >> 4, h = cmb & 15;

    short8 bOnes;                         // L = P @ ones-column = rowsum
    #pragma unroll
    for (int j = 0; j < 8; ++j) bOnes[j] = (col == 0) ? (short)0x3F80 : (short)0;

    const size_t rs = (size_t)3 * C;
    const short* qbase = qkvb + (size_t)b * K * rs + h * DH;
    const short* kbase = qbase + C;
    const short* vbase = vt + (size_t)(b * 16 + h) * DH * K;

    const int srow = lane & 56;           // staging row group
    const int goff = (lane & 7) * 8;      // elem offset within row
    const int loff = lane * 8;            // contiguous LDS dest (shorts)

    auto run = [&](int T) {
        const int t0 = T * 64;

        short8 aQ[4][2];
        #pragma unroll
        for (int qg = 0; qg < 4; ++qg) {
            const short* qp = qbase + (size_t)(t0 + qg * 16 + col) * rs;
            aQ[qg][0] = *(const short8*)(qp + quad * 8);
            aQ[qg][1] = *(const short8*)(qp + 32 + quad * 8);
        }
        f32x4 O[4][4] = {};
        f32x4 L4[4] = {};

        // ---- main loop: this wave's chunks only; NO barriers ----
        for (int ci = w; ci <= T; ci += 4) {
            const int kc = ci * 64;
            // stage K rows (bit-swap slot perm via 1040B blocks) + V^T rows
            #pragma unroll
            for (int c2 = 0; c2 < 8; ++c2) {
                GLL16(kbase + (size_t)(kc + srow + c2) * rs + goff, Ksw + c2 * 520 + loff);
                GLL16(vbase + (size_t)(srow + c2) * K + kc + goff,  Vsw + c2 * 520 + loff);
            }
            asm volatile("s_waitcnt vmcnt(0)" ::: "memory");

            // fragments read ONCE, reused by all 4 q-groups
            short8 bK[4][2], bV[4][2];
            #pragma unroll
            for (int nb = 0; nb < 4; ++nb) {     // key = col*4+nb
                const int ka = (4 * (col & 1) + nb) * 520 + (col >> 1) * 64 + quad * 8;
                bK[nb][0] = *(const short8*)&Ksw[ka];
                bK[nb][1] = *(const short8*)&Ksw[ka + 32];
            }
            #pragma unroll
            for (int db = 0; db < 4; ++db) {     // d = db*16+col
                const int va = (col & 7) * 520 + (db * 2 + (col >> 3)) * 64 + quad * 8;
                bV[db][0] = *(const short8*)&Vsw[va];
                bV[db][1] = *(const short8*)&Vsw[va + 32];
            }

            const bool diag = (kc == t0);
            #pragma unroll
            for (int qg = 0; qg < 4; ++qg) {
                f32x4 S[4] = {};
                #pragma unroll
                for (int nb = 0; nb < 4; ++nb) {
                    S[nb] = __builtin_amdgcn_mfma_f32_16x16x32_bf16(aQ[qg][0], bK[nb][0], S[nb], 0, 0, 0);
                    S[nb] = __builtin_amdgcn_mfma_f32_16x16x32_bf16(aQ[qg][1], bK[nb][1], S[nb], 0, 0, 0);
                }
                if (!diag) {
                    #pragma unroll
                    for (int i = 0; i < 4; ++i) {
                        int2v pw = { pack2bf(EXP2(S[0][i]), EXP2(S[1][i])),
                                     pack2bf(EXP2(S[2][i]), EXP2(S[3][i])) };
                        *(int2v*)&Ptw[(quad * 4 + i) * 72 + col * 4] = pw;
                    }
                } else {
                    const int qrel = qg * 16 + quad * 4;   // + i ; key = col*4+nb
                    #pragma unroll
                    for (int i = 0; i < 4; ++i) {
                        float s0 = (col * 4 + 0 <= qrel + i) ? S[0][i] : -INFINITY;
                        float s1 = (col * 4 + 1 <= qrel + i) ? S[1][i] : -INFINITY;
                        float s2 = (col * 4 + 2 <= qrel + i) ? S[2][i] : -INFINITY;
                        float s3 = (col * 4 + 3 <= qrel + i) ? S[3][i] : -INFINITY;
                        int2v pw = { pack2bf(EXP2(s0), EXP2(s1)),
                                     pack2bf(EXP2(s2), EXP2(s3)) };
                        *(int2v*)&Ptw[(quad * 4 + i) * 72 + col * 4] = pw;
                    }
                }
                asm volatile("s_waitcnt lgkmcnt(0)" ::: "memory");
                #pragma unroll
                for (int half = 0; half < 2; ++half) {
                    short8 aP = *(const short8*)&Ptw[col * 72 + half * 32 + quad * 8];
                    #pragma unroll
                    for (int db = 0; db < 4; ++db)
                        O[qg][db] = __builtin_amdgcn_mfma_f32_16x16x32_bf16(aP, bV[db][half], O[qg][db], 0, 0, 0);
                    L4[qg] = __builtin_amdgcn_mfma_f32_16x16x32_bf16(aP, bOnes, L4[qg], 0, 0, 0);
                }
            }
        }

        // ---- cross-wave reduction of partial O / L ----
        __syncthreads();
        for (int ww = 0; ww < 4; ++ww) {
            if (w == ww) {
                #pragma unroll
                for (int qg = 0; qg < 4; ++qg)
                    #pragma unroll
                    for (int i = 0; i < 4; ++i) {
                        const int row = qg * 16 + quad * 4 + i;
                        #pragma unroll
                        for (int db = 0; db < 4; ++db) {
                            float v = O[qg][db][i];
                            if (ww == 0) Or[row * 68 + db * 16 + col] = v;
                            else         Or[row * 68 + db * 16 + col] += v;
                        }
                        if (col == 0) {
                            if (ww == 0) Or[row * 68 + 64] = L4[qg][i];
                            else         Or[row * 68 + 64] += L4[qg][i];
                        }
                    }
            }
            __syncthreads();
        }

        // ---- normalize + store: wave w -> rows [w*16, w*16+16) ----
        #pragma unroll
        for (int rstep = 0; rstep < 4; ++rstep) {
            const int row = w * 16 + rstep * 4 + quad;
            f32x4 ov = *(const f32x4*)&Or[row * 68 + col * 4];
            const float inv = 1.f / Or[row * 68 + 64];
            int2v o2 = { pack2bf(ov[0] * inv, ov[1] * inv),
                         pack2bf(ov[2] * inv, ov[3] * inv) };
            *(int2v*)(y + ((size_t)b * K + t0 + row) * C + h * DH + col * 4) = o2;
        }
        __syncthreads();   // protect Or before next tile restages
    };

    run(g);
    run(31 - g);
}

// ------------------------------- launch -------------------------------------
extern "C" void kernel_launch(void* const* d_in, const int* in_sizes, int n_in,
                              void* d_out, int out_size, void* d_ws, size_t ws_size,
                              hipStream_t stream)
{
    const float* x      = (const float*)d_in[0];
    const float* W_qkv  = (const float*)d_in[1];
    const float* b_qkv  = (const float*)d_in[2];
    const float* W_proj = (const float*)d_in[3];
    const float* b_proj = (const float*)d_in[4];

    const int B = 2, K = 2048, C = 1024, H = 16;
    const int M = B * K;   // 4096
    const float C2 = 0.18033688f;   // (1/sqrt(64)) * log2(e)

    char* ws = (char*)d_ws;
    short* xb    = (short*)ws;  ws += (size_t)M * C * 2;
    short* Wt1   = (short*)ws;  ws += (size_t)3 * C * C * 2;
    short* Wt2   = (short*)ws;  ws += (size_t)C * C * 2;
    short* qkvb  = (short*)ws;  ws += (size_t)M * 3 * C * 2;
    short* yb    = (short*)ws;  ws += (size_t)M * C * 2;
    short* vtb   = (short*)ws;

    // prep (fused): cast x + transpose both weights
    const int nbx = (M * C) / 1024;
    const int nb1 = (3 * C / 32) * (C / 32);
    const int nb2 = (C / 32) * (C / 32);
    prep_kernel<<<nbx + nb1 + nb2, 256, 0, stream>>>(x, xb, M * C, W_qkv, Wt1, W_proj, Wt2, C);

    // 1) qkv = x @ W_qkv + b_qkv  (bf16 out; Q columns pre-scaled by C2)
    dim3 g1((3 * C) / GN, M / GM);
    gemm_mfma_kernel<short><<<g1, 256, 0, stream>>>(xb, Wt1, b_qkv, qkvb, M, 3 * C, C, C, C2);

    // 1b) V transpose for flash B-fragments
    dim3 gv(K / 64, H, B);
    vtrans_kernel<<<gv, 256, 0, stream>>>(qkvb, vtb, K, C);

    // 2) flash attention -> yb (bf16); 1-D grid: idx = pair*32 + (b*16+h)
    const int NPAIR = (K / 64) / 2;   // 16
    flash_mfma_kernel<<<dim3(NPAIR * 32), 256, 0, stream>>>(qkvb, vtb, yb, K, C);

    // 3) out = y @ W_proj + b_proj (fp32 out)
    dim3 g3(C / GN, M / GM);
    gemm_mfma_kernel<float><<<g3, 256, 0, stream>>>(yb, Wt2, b_proj, (float*)d_out, M, C, C, 0, 1.f);
}